// Round 1
// baseline (337.360 us; speedup 1.0000x reference)
//
#include <hip/hip_runtime.h>

// out[e] = dot(x[src[e]], x[dst[e]]), D=128 f32.
// 16 lanes per edge: lane l loads float4 #l and #(l+16) of each 128-float row
// (512 B per row, fully coalesced across the 16-lane group), 8 FMAs, then a
// 4-step shfl_xor reduction within the 16-lane group.
__global__ __launch_bounds__(256)
void sip_dot_kernel(const float* __restrict__ x,
                    const int* __restrict__ src,
                    const int* __restrict__ dst,
                    float* __restrict__ out,
                    int E) {
    const int tid  = blockIdx.x * blockDim.x + threadIdx.x;
    const int edge = tid >> 4;        // 16 lanes per edge
    const int lane = tid & 15;

    if (tid == 0) {
        // trailing int32 zeros((1,1)) placeholder — bit pattern 0 either way
        out[E] = 0.0f;
    }
    if (edge >= E) return;

    const int s = src[edge];
    const int d = dst[edge];

    const float4* xs = (const float4*)(x + (size_t)s * 128);
    const float4* xd = (const float4*)(x + (size_t)d * 128);

    // load0: lanes 0..15 cover bytes [0,256) of the row; load1: [256,512)
    float4 a0 = xs[lane];
    float4 a1 = xs[lane + 16];
    float4 b0 = xd[lane];
    float4 b1 = xd[lane + 16];

    float sum = a0.x * b0.x + a0.y * b0.y + a0.z * b0.z + a0.w * b0.w
              + a1.x * b1.x + a1.y * b1.y + a1.z * b1.z + a1.w * b1.w;

    // reduce across the 16-lane group (stays inside the group for masks 1,2,4,8)
    sum += __shfl_xor(sum, 8, 64);
    sum += __shfl_xor(sum, 4, 64);
    sum += __shfl_xor(sum, 2, 64);
    sum += __shfl_xor(sum, 1, 64);

    if (lane == 0) out[edge] = sum;
}

extern "C" void kernel_launch(void* const* d_in, const int* in_sizes, int n_in,
                              void* d_out, int out_size, void* d_ws, size_t ws_size,
                              hipStream_t stream) {
    const float* x   = (const float*)d_in[0];
    const int*   ei  = (const int*)d_in[1];
    const int    E   = in_sizes[1] / 2;     // edge_index is (2, E)
    const int*   src = ei;
    const int*   dst = ei + E;
    float*       out = (float*)d_out;

    const int threads = 256;
    const long long total = (long long)E * 16;
    const int blocks = (int)((total + threads - 1) / threads);
    sip_dot_kernel<<<blocks, threads, 0, stream>>>(x, src, dst, out, E);
}

// Round 2
// 219.285 us; speedup vs baseline: 1.5385x; 1.5385x over previous
//
#include <hip/hip_runtime.h>

typedef __attribute__((ext_vector_type(8))) _Float16 half8;
typedef __attribute__((ext_vector_type(4))) _Float16 half4;

// Pass 1: compact x (N*D fp32) -> fp16 in workspace. 4 elems/thread.
__global__ __launch_bounds__(256)
void sip_convert_kernel(const float* __restrict__ x,
                        _Float16* __restrict__ xh,
                        int total4) {
    int i = blockIdx.x * blockDim.x + threadIdx.x;
    if (i >= total4) return;
    float4 v = ((const float4*)x)[i];
    half4 h;
    h[0] = (_Float16)v.x; h[1] = (_Float16)v.y;
    h[2] = (_Float16)v.z; h[3] = (_Float16)v.w;
    ((half4*)xh)[i] = h;   // 8 B store, coalesced
}

// Pass 2: out[e] = dot(xh[src[e]], xh[dst[e]]), D=128 fp16, fp32 accumulate.
// 16 lanes per edge: lane l loads halves [8l, 8l+8) of each row (16 B),
// one dwordx4 per row per lane (256 B per row across the 16-lane group).
__global__ __launch_bounds__(256)
void sip_dot_f16_kernel(const _Float16* __restrict__ xh,
                        const int* __restrict__ src,
                        const int* __restrict__ dst,
                        float* __restrict__ out,
                        int E) {
    const int tid  = blockIdx.x * blockDim.x + threadIdx.x;
    const int edge = tid >> 4;
    const int lane = tid & 15;

    if (tid == 0) out[E] = 0.0f;   // trailing int32 zeros((1,1)) placeholder
    if (edge >= E) return;

    const int s = src[edge];
    const int d = dst[edge];

    half8 a = ((const half8*)(xh + (size_t)s * 128))[lane];
    half8 b = ((const half8*)(xh + (size_t)d * 128))[lane];

    float sum = 0.0f;
#pragma unroll
    for (int j = 0; j < 8; ++j)
        sum += (float)a[j] * (float)b[j];

    sum += __shfl_xor(sum, 8, 64);
    sum += __shfl_xor(sum, 4, 64);
    sum += __shfl_xor(sum, 2, 64);
    sum += __shfl_xor(sum, 1, 64);

    if (lane == 0) out[edge] = sum;
}

// Fallback (proven R1 kernel): pure fp32 gather, if ws can't hold fp16 copy.
__global__ __launch_bounds__(256)
void sip_dot_f32_kernel(const float* __restrict__ x,
                        const int* __restrict__ src,
                        const int* __restrict__ dst,
                        float* __restrict__ out,
                        int E) {
    const int tid  = blockIdx.x * blockDim.x + threadIdx.x;
    const int edge = tid >> 4;
    const int lane = tid & 15;

    if (tid == 0) out[E] = 0.0f;
    if (edge >= E) return;

    const int s = src[edge];
    const int d = dst[edge];

    const float4* xs = (const float4*)(x + (size_t)s * 128);
    const float4* xd = (const float4*)(x + (size_t)d * 128);
    float4 a0 = xs[lane];
    float4 a1 = xs[lane + 16];
    float4 b0 = xd[lane];
    float4 b1 = xd[lane + 16];

    float sum = a0.x * b0.x + a0.y * b0.y + a0.z * b0.z + a0.w * b0.w
              + a1.x * b1.x + a1.y * b1.y + a1.z * b1.z + a1.w * b1.w;

    sum += __shfl_xor(sum, 8, 64);
    sum += __shfl_xor(sum, 4, 64);
    sum += __shfl_xor(sum, 2, 64);
    sum += __shfl_xor(sum, 1, 64);

    if (lane == 0) out[edge] = sum;
}

extern "C" void kernel_launch(void* const* d_in, const int* in_sizes, int n_in,
                              void* d_out, int out_size, void* d_ws, size_t ws_size,
                              hipStream_t stream) {
    const float* x   = (const float*)d_in[0];
    const int*   ei  = (const int*)d_in[1];
    const int    ND  = in_sizes[0];         // N*D
    const int    E   = in_sizes[1] / 2;     // edge_index is (2, E)
    const int*   src = ei;
    const int*   dst = ei + E;
    float*       out = (float*)d_out;

    const int threads = 256;
    const long long total  = (long long)E * 16;
    const int gather_blocks = (int)((total + threads - 1) / threads);

    if (ws_size >= (size_t)ND * sizeof(_Float16)) {
        _Float16* xh = (_Float16*)d_ws;
        const int total4 = ND / 4;
        sip_convert_kernel<<<(total4 + threads - 1) / threads, threads, 0, stream>>>(
            x, xh, total4);
        sip_dot_f16_kernel<<<gather_blocks, threads, 0, stream>>>(
            xh, src, dst, out, E);
    } else {
        sip_dot_f32_kernel<<<gather_blocks, threads, 0, stream>>>(
            x, src, dst, out, E);
    }
}

// Round 3
// 202.272 us; speedup vs baseline: 1.6679x; 1.0841x over previous
//
#include <hip/hip_runtime.h>

// Pass 1: quantize x (N rows x 128 f32) -> int8 with per-row scale.
// One 64-lane wave per row: lane l handles elements [2l, 2l+1].
__global__ __launch_bounds__(256)
void sip_quant_kernel(const float* __restrict__ x,
                      char* __restrict__ xq,
                      float* __restrict__ scales,
                      int N) {
    const int row  = blockIdx.x * 4 + (threadIdx.x >> 6);
    const int lane = threadIdx.x & 63;
    if (row >= N) return;

    float2 v = ((const float2*)(x + (size_t)row * 128))[lane];
    float m = fmaxf(fabsf(v.x), fabsf(v.y));
#pragma unroll
    for (int off = 32; off > 0; off >>= 1)
        m = fmaxf(m, __shfl_xor(m, off, 64));

    const float inv = (m > 0.0f) ? 127.0f / m : 0.0f;
    const int qa = (int)rintf(v.x * inv);
    const int qb = (int)rintf(v.y * inv);
    const unsigned short p =
        (unsigned short)((qa & 0xFF) | ((qb & 0xFF) << 8));
    ((unsigned short*)(xq + (size_t)row * 128))[lane] = p;  // 2 B/lane, contiguous
    if (lane == 0) scales[row] = m * (1.0f / 127.0f);
}

__device__ __forceinline__ int dot4_i8(int a, int b, int c) {
#if __has_builtin(__builtin_amdgcn_sdot4)
    return __builtin_amdgcn_sdot4(a, b, c, false);
#else
    int r = c;
    r += ((a << 24) >> 24) * ((b << 24) >> 24);
    r += ((a << 16) >> 24) * ((b << 16) >> 24);
    r += ((a <<  8) >> 24) * ((b <<  8) >> 24);
    r += ( a        >> 24) * ( b        >> 24);
    return r;
#endif
}

// Pass 2: out[e] = scale_s*scale_d * idot(xq[src[e]], xq[dst[e]]).
// 16 lanes per edge, 8 int8 per lane per row (8 B load, 128 B/row per group).
__global__ __launch_bounds__(256)
void sip_dot_q8_kernel(const char* __restrict__ xq,
                       const float* __restrict__ scales,
                       const int* __restrict__ src,
                       const int* __restrict__ dst,
                       float* __restrict__ out,
                       int E) {
    const int tid  = blockIdx.x * blockDim.x + threadIdx.x;
    const int edge = tid >> 4;
    const int lane = tid & 15;

    if (tid == 0) out[E] = 0.0f;   // trailing int32 zeros((1,1)) placeholder
    if (edge >= E) return;

    const int s = src[edge];
    const int d = dst[edge];

    int2 a = ((const int2*)(xq + (size_t)s * 128))[lane];
    int2 b = ((const int2*)(xq + (size_t)d * 128))[lane];

    int isum = dot4_i8(a.x, b.x, 0);
    isum     = dot4_i8(a.y, b.y, isum);

    isum += __shfl_xor(isum, 8, 64);
    isum += __shfl_xor(isum, 4, 64);
    isum += __shfl_xor(isum, 2, 64);
    isum += __shfl_xor(isum, 1, 64);

    if (lane == 0) out[edge] = (float)isum * scales[s] * scales[d];
}

// Fallback (proven R1 kernel): pure fp32 gather, if ws too small.
__global__ __launch_bounds__(256)
void sip_dot_f32_kernel(const float* __restrict__ x,
                        const int* __restrict__ src,
                        const int* __restrict__ dst,
                        float* __restrict__ out,
                        int E) {
    const int tid  = blockIdx.x * blockDim.x + threadIdx.x;
    const int edge = tid >> 4;
    const int lane = tid & 15;

    if (tid == 0) out[E] = 0.0f;
    if (edge >= E) return;

    const int s = src[edge];
    const int d = dst[edge];
    const float4* xs = (const float4*)(x + (size_t)s * 128);
    const float4* xd = (const float4*)(x + (size_t)d * 128);
    float4 a0 = xs[lane];
    float4 a1 = xs[lane + 16];
    float4 b0 = xd[lane];
    float4 b1 = xd[lane + 16];

    float sum = a0.x * b0.x + a0.y * b0.y + a0.z * b0.z + a0.w * b0.w
              + a1.x * b1.x + a1.y * b1.y + a1.z * b1.z + a1.w * b1.w;

    sum += __shfl_xor(sum, 8, 64);
    sum += __shfl_xor(sum, 4, 64);
    sum += __shfl_xor(sum, 2, 64);
    sum += __shfl_xor(sum, 1, 64);

    if (lane == 0) out[edge] = sum;
}

extern "C" void kernel_launch(void* const* d_in, const int* in_sizes, int n_in,
                              void* d_out, int out_size, void* d_ws, size_t ws_size,
                              hipStream_t stream) {
    const float* x   = (const float*)d_in[0];
    const int*   ei  = (const int*)d_in[1];
    const int    ND  = in_sizes[0];         // N*D, D=128
    const int    N   = ND / 128;
    const int    E   = in_sizes[1] / 2;     // edge_index is (2, E)
    const int*   src = ei;
    const int*   dst = ei + E;
    float*       out = (float*)d_out;

    const int threads = 256;
    const long long total   = (long long)E * 16;
    const int gather_blocks = (int)((total + threads - 1) / threads);

    const size_t need = (size_t)ND + (size_t)N * sizeof(float);
    if (ws_size >= need) {
        char*  xq     = (char*)d_ws;
        float* scales = (float*)((char*)d_ws + (size_t)ND);
        sip_quant_kernel<<<(N + 3) / 4, threads, 0, stream>>>(x, xq, scales, N);
        sip_dot_q8_kernel<<<gather_blocks, threads, 0, stream>>>(
            xq, scales, src, dst, out, E);
    } else {
        sip_dot_f32_kernel<<<gather_blocks, threads, 0, stream>>>(
            x, src, dst, out, E);
    }
}

// Round 4
// 156.947 us; speedup vs baseline: 2.1495x; 1.2888x over previous
//
#include <hip/hip_runtime.h>

// Pass 1: quantize x (N rows x 128 f32) -> int8 with per-row scale.
// One 64-lane wave per row: lane l handles elements [2l, 2l+1].
__global__ __launch_bounds__(256)
void sip_quant_kernel(const float* __restrict__ x,
                      char* __restrict__ xq,
                      float* __restrict__ scales,
                      int N) {
    const int row  = blockIdx.x * 4 + (threadIdx.x >> 6);
    const int lane = threadIdx.x & 63;
    if (row >= N) return;

    float2 v = ((const float2*)(x + (size_t)row * 128))[lane];
    float m = fmaxf(fabsf(v.x), fabsf(v.y));
#pragma unroll
    for (int off = 32; off > 0; off >>= 1)
        m = fmaxf(m, __shfl_xor(m, off, 64));

    const float inv = (m > 0.0f) ? 127.0f / m : 0.0f;
    const int qa = (int)rintf(v.x * inv);
    const int qb = (int)rintf(v.y * inv);
    const unsigned short p =
        (unsigned short)((qa & 0xFF) | ((qb & 0xFF) << 8));
    ((unsigned short*)(xq + (size_t)row * 128))[lane] = p;
    if (lane == 0) scales[row] = m * (1.0f / 127.0f);
}

__device__ __forceinline__ int dot4_i8(int a, int b, int c) {
#if __has_builtin(__builtin_amdgcn_sdot4)
    return __builtin_amdgcn_sdot4(a, b, c, false);
#else
    int r = c;
    r += ((a << 24) >> 24) * ((b << 24) >> 24);
    r += ((a << 16) >> 24) * ((b << 16) >> 24);
    r += ((a <<  8) >> 24) * ((b <<  8) >> 24);
    r += ( a        >> 24) * ( b        >> 24);
    return r;
#endif
}

__device__ __forceinline__ int dot16_i8(int4 a, int4 b) {
    int r = dot4_i8(a.x, b.x, 0);
    r = dot4_i8(a.y, b.y, r);
    r = dot4_i8(a.z, b.z, r);
    r = dot4_i8(a.w, b.w, r);
    return r;
}

// Pass 2 (batched): 8 lanes per edge, 4 edges per 8-lane group.
// Lane l loads bytes [16l,16l+16) of each row (dwordx4); 8 independent
// gathers in flight per thread. Requires E % 4 == 0.
__global__ __launch_bounds__(256)
void sip_dot_q8x4_kernel(const char* __restrict__ xq,
                         const float* __restrict__ scales,
                         const int* __restrict__ src,
                         const int* __restrict__ dst,
                         float* __restrict__ out,
                         int E) {
    const int tid  = blockIdx.x * blockDim.x + threadIdx.x;
    const int grp  = tid >> 3;
    const int lane = tid & 7;
    const int e0   = grp * 4;

    if (tid == 0) out[E] = 0.0f;   // trailing int32 zeros((1,1)) placeholder
    if (e0 >= E) return;

    // broadcast 16-B idx loads (same addr across the 8-lane group)
    const int4 s4 = *(const int4*)(src + e0);
    const int4 d4 = *(const int4*)(dst + e0);

    // 8 independent 16-B gathers
    const int4 a0 = ((const int4*)(xq + (size_t)s4.x * 128))[lane];
    const int4 b0 = ((const int4*)(xq + (size_t)d4.x * 128))[lane];
    const int4 a1 = ((const int4*)(xq + (size_t)s4.y * 128))[lane];
    const int4 b1 = ((const int4*)(xq + (size_t)d4.y * 128))[lane];
    const int4 a2 = ((const int4*)(xq + (size_t)s4.z * 128))[lane];
    const int4 b2 = ((const int4*)(xq + (size_t)d4.z * 128))[lane];
    const int4 a3 = ((const int4*)(xq + (size_t)s4.w * 128))[lane];
    const int4 b3 = ((const int4*)(xq + (size_t)d4.w * 128))[lane];

    int i0 = dot16_i8(a0, b0);
    int i1 = dot16_i8(a1, b1);
    int i2 = dot16_i8(a2, b2);
    int i3 = dot16_i8(a3, b3);

    // reduce each across the 8-lane group
#pragma unroll
    for (int off = 4; off > 0; off >>= 1) {
        i0 += __shfl_xor(i0, off, 64);
        i1 += __shfl_xor(i1, off, 64);
        i2 += __shfl_xor(i2, off, 64);
        i3 += __shfl_xor(i3, off, 64);
    }

    if (lane == 0) {
        float4 r;
        r.x = (float)i0 * scales[s4.x] * scales[d4.x];
        r.y = (float)i1 * scales[s4.y] * scales[d4.y];
        r.z = (float)i2 * scales[s4.z] * scales[d4.z];
        r.w = (float)i3 * scales[s4.w] * scales[d4.w];
        *(float4*)(out + e0) = r;   // e0 % 4 == 0 -> 16-B aligned
    }
}

// Unbatched q8 kernel (R3, proven): used when E % 4 != 0.
__global__ __launch_bounds__(256)
void sip_dot_q8_kernel(const char* __restrict__ xq,
                       const float* __restrict__ scales,
                       const int* __restrict__ src,
                       const int* __restrict__ dst,
                       float* __restrict__ out,
                       int E) {
    const int tid  = blockIdx.x * blockDim.x + threadIdx.x;
    const int edge = tid >> 4;
    const int lane = tid & 15;

    if (tid == 0) out[E] = 0.0f;
    if (edge >= E) return;

    const int s = src[edge];
    const int d = dst[edge];

    int2 a = ((const int2*)(xq + (size_t)s * 128))[lane];
    int2 b = ((const int2*)(xq + (size_t)d * 128))[lane];

    int isum = dot4_i8(a.x, b.x, 0);
    isum     = dot4_i8(a.y, b.y, isum);

    isum += __shfl_xor(isum, 8, 64);
    isum += __shfl_xor(isum, 4, 64);
    isum += __shfl_xor(isum, 2, 64);
    isum += __shfl_xor(isum, 1, 64);

    if (lane == 0) out[edge] = (float)isum * scales[s] * scales[d];
}

// Fallback (proven R1 kernel): pure fp32 gather, if ws too small.
__global__ __launch_bounds__(256)
void sip_dot_f32_kernel(const float* __restrict__ x,
                        const int* __restrict__ src,
                        const int* __restrict__ dst,
                        float* __restrict__ out,
                        int E) {
    const int tid  = blockIdx.x * blockDim.x + threadIdx.x;
    const int edge = tid >> 4;
    const int lane = tid & 15;

    if (tid == 0) out[E] = 0.0f;
    if (edge >= E) return;

    const int s = src[edge];
    const int d = dst[edge];
    const float4* xs = (const float4*)(x + (size_t)s * 128);
    const float4* xd = (const float4*)(x + (size_t)d * 128);
    float4 a0 = xs[lane];
    float4 a1 = xs[lane + 16];
    float4 b0 = xd[lane];
    float4 b1 = xd[lane + 16];

    float sum = a0.x * b0.x + a0.y * b0.y + a0.z * b0.z + a0.w * b0.w
              + a1.x * b1.x + a1.y * b1.y + a1.z * b1.z + a1.w * b1.w;

    sum += __shfl_xor(sum, 8, 64);
    sum += __shfl_xor(sum, 4, 64);
    sum += __shfl_xor(sum, 2, 64);
    sum += __shfl_xor(sum, 1, 64);

    if (lane == 0) out[edge] = sum;
}

extern "C" void kernel_launch(void* const* d_in, const int* in_sizes, int n_in,
                              void* d_out, int out_size, void* d_ws, size_t ws_size,
                              hipStream_t stream) {
    const float* x   = (const float*)d_in[0];
    const int*   ei  = (const int*)d_in[1];
    const int    ND  = in_sizes[0];         // N*D, D=128
    const int    N   = ND / 128;
    const int    E   = in_sizes[1] / 2;     // edge_index is (2, E)
    const int*   src = ei;
    const int*   dst = ei + E;
    float*       out = (float*)d_out;

    const int threads = 256;
    const size_t need = (size_t)ND + (size_t)N * sizeof(float);

    if (ws_size >= need) {
        char*  xq     = (char*)d_ws;
        float* scales = (float*)((char*)d_ws + (size_t)ND);
        sip_quant_kernel<<<(N + 3) / 4, threads, 0, stream>>>(x, xq, scales, N);
        if ((E & 3) == 0) {
            const long long total = (long long)(E / 4) * 8;
            const int blocks = (int)((total + threads - 1) / threads);
            sip_dot_q8x4_kernel<<<blocks, threads, 0, stream>>>(
                xq, scales, src, dst, out, E);
        } else {
            const long long total = (long long)E * 16;
            const int blocks = (int)((total + threads - 1) / threads);
            sip_dot_q8_kernel<<<blocks, threads, 0, stream>>>(
                xq, scales, src, dst, out, E);
        }
    } else {
        const long long total = (long long)E * 16;
        const int blocks = (int)((total + threads - 1) / threads);
        sip_dot_f32_kernel<<<blocks, threads, 0, stream>>>(
            x, src, dst, out, E);
    }
}